// Round 3
// baseline (100.020 us; speedup 1.0000x reference)
//
#include <hip/hip_runtime.h>

// BlockConv: out[b,n,i,f] = sum_{dd=0..2} sum_{|i-j|<=1} w[dd][i][j] * x[b,n+dd-1,j,f]
// B=4, NB=256, BS=256, FEAT=256, fp32. Memory-bound; floor ~512MB @6.3TB/s ~ 81us.
// R3: R2 + XCD-aware bijective swizzle (T1): each XCD owns a contiguous run of
//     n-blocks so halo reads (n-1,n,n+1) hit the same per-XCD L2.

#define NB   256
#define BS   256
#define F4   64                      // FEAT/4
#define RPT  8                       // output rows per thread
#define TY   4
#define ROWS_PER_WG (RPT * TY)       // 32
#define CHUNKS (BS / ROWS_PER_WG)    // 8
#define NXCD 8
#define NWG  (4 * NB * CHUNKS)       // 8192, divisible by 8

typedef float f32x4 __attribute__((ext_vector_type(4)));

__global__ __launch_bounds__(256)
void blockconv_kernel(const float* __restrict__ x,
                      const float* __restrict__ w,
                      float* __restrict__ out)
{
    const int tx = threadIdx.x;            // 0..63 : float4 feature index
    const int ty = threadIdx.y;            // 0..3  : row group (wave-uniform)

    // ---- T1: XCD-aware swizzle. wg%8 = XCD (HW round-robin); give each XCD
    // a contiguous range of g = (b,n,chunk) with chunk fastest, n next.
    const int wg   = blockIdx.x;
    const int xcd  = wg & (NXCD - 1);
    const int loc  = wg >> 3;                    // 0..1023
    const int g    = xcd * (NWG / NXCD) + loc;   // bijective remap

    const int chunk = g & (CHUNKS - 1);
    const int n     = (g >> 3) & (NB - 1);
    const int b     = g >> 11;

    const int i_base = chunk * ROWS_PER_WG + ty * RPT;
    const int jlo    = i_base - 1;
    const int jlo_cl = jlo < 0 ? 0 : jlo;              // clamp first window row
    const bool lo_ok = (jlo >= 0);
    const bool hi_ok = (jlo + RPT + 1) < BS;           // last window row valid?

    const f32x4* __restrict__ x4 = (const f32x4*)x;
    f32x4* __restrict__ out4     = (f32x4*)out;

    f32x4 acc[RPT];
#pragma unroll
    for (int i = 0; i < RPT; ++i) acc[i] = (f32x4)(0.f);

#pragma unroll
    for (int dd = 0; dd < 3; ++dd) {
        const int nn_raw = n + dd - 1;
        const bool d_ok  = (nn_raw >= 0) & (nn_raw < NB);
        const int  nn    = nn_raw < 0 ? 0 : (nn_raw >= NB ? NB - 1 : nn_raw);

        const f32x4* __restrict__ xblk = x4 + ((size_t)(b * NB + nn) * BS) * F4 + tx;
        const float* __restrict__  wblk = w + (size_t)dd * BS * BS;

        // ---- window loads: RPT+2 independent 1KiB wave-loads, issued back-to-back
        f32x4 v[RPT + 2];
        v[0] = xblk[(size_t)jlo_cl * F4];
#pragma unroll
        for (int jj = 1; jj <= RPT; ++jj)
            v[jj] = xblk[(size_t)(jlo + jj) * F4];
        v[RPT + 1] = xblk[(size_t)(hi_ok ? jlo + RPT + 1 : jlo + RPT) * F4];
        if (!lo_ok) v[0]       = (f32x4)(0.f);
        if (!hi_ok) v[RPT + 1] = (f32x4)(0.f);

        // ---- weights: wave-uniform scalars -> SGPRs via readfirstlane
        float wv[RPT][3];
#pragma unroll
        for (int ii = 0; ii < RPT; ++ii) {
            const int irow = i_base + ii;
#pragma unroll
            for (int c = 0; c < 3; ++c) {
                int j = irow - 1 + c;
                const bool j_ok = (j >= 0) & (j < BS);
                j = j < 0 ? 0 : (j >= BS ? BS - 1 : j);
                float raw = wblk[(size_t)irow * BS + j];
                raw = (d_ok & j_ok) ? raw : 0.f;       // mask OOB block / OOB row
                const int bits = __builtin_amdgcn_readfirstlane(__float_as_int(raw));
                wv[ii][c] = __int_as_float(bits);
            }
        }

        // ---- FMAs (all indices compile-time)
#pragma unroll
        for (int ii = 0; ii < RPT; ++ii) {
#pragma unroll
            for (int c = 0; c < 3; ++c) {
                const float s  = wv[ii][c];
                const f32x4 vv = v[ii + c];
                acc[ii].x = fmaf(s, vv.x, acc[ii].x);
                acc[ii].y = fmaf(s, vv.y, acc[ii].y);
                acc[ii].z = fmaf(s, vv.z, acc[ii].z);
                acc[ii].w = fmaf(s, vv.w, acc[ii].w);
            }
        }
    }

    const size_t obase = ((size_t)(b * NB + n) * BS + i_base) * F4 + tx;
#pragma unroll
    for (int i = 0; i < RPT; ++i)
        __builtin_nontemporal_store(acc[i], &out4[obase + (size_t)i * F4]);
}

extern "C" void kernel_launch(void* const* d_in, const int* in_sizes, int n_in,
                              void* d_out, int out_size, void* d_ws, size_t ws_size,
                              hipStream_t stream) {
    const float* x = (const float*)d_in[0];     // [4, 65536, 256] f32
    const float* w = (const float*)d_in[1];     // [3, 256, 256]   f32
    float* out = (float*)d_out;                 // [4, 65536, 256] f32

    dim3 block(64, TY);
    blockconv_kernel<<<NWG, block, 0, stream>>>(x, w, out);
}

// Round 4
// 83.907 us; speedup vs baseline: 1.1920x; 1.1920x over previous
//
#include <hip/hip_runtime.h>

// BlockConv: out[b,n,i,f] = sum_{dd=0..2} sum_{|i-j|<=1} w[dd][i][j] * x[b,n+dd-1,j,f]
// B=4, NB=256, BS=256, FEAT=256, fp32. Memory-bound; floor ~512MB @6.3TB/s ~ 81us.
// R4: revert XCD swizzle (R3 regressed). Weights staged in LDS once per WG
//     (masked there), read via ds_read_b128 -> weight traffic off the vmcnt
//     queue; dd-groups software-pipelined (load v0,v1; fma0; load v2; fma1; fma2).

#define NB   256
#define BS   256
#define F4   64                      // FEAT/4
#define RPT  8                       // output rows per thread
#define TY   4
#define ROWS_PER_WG (RPT * TY)       // 32
#define CHUNKS (BS / ROWS_PER_WG)    // 8
#define NWG  (4 * NB * CHUNKS)       // 8192

typedef float f32x4 __attribute__((ext_vector_type(4)));

__global__ __launch_bounds__(256)
void blockconv_kernel(const float* __restrict__ x,
                      const float* __restrict__ w,
                      float* __restrict__ out)
{
    const int tx = threadIdx.x;            // 0..63 : float4 feature index
    const int ty = threadIdx.y;            // 0..3  : row group (wave-uniform)
    const int wg = blockIdx.x;

    const int chunk = wg & (CHUNKS - 1);
    const int n     = (wg >> 3) & (NB - 1);
    const int b     = wg >> 11;

    // ---- stage masked weights in LDS: wlds[row][dd*4 + c], stride 16 floats
    __shared__ float wlds[ROWS_PER_WG][16];
    {
        const int tid = ty * 64 + tx;      // 0..255
#pragma unroll
        for (int e0 = 0; e0 < 2; ++e0) {
            const int e  = tid + e0 * 256; // 0..511
            const int r  = e >> 4;
            const int q  = e & 15;
            const int dd = q >> 2;
            const int c  = q & 3;
            const int irow   = chunk * ROWS_PER_WG + r;
            const int nn_raw = n + dd - 1;
            int j = irow - 1 + c;
            const bool ok = (dd < 3) & (c < 3) &
                            (nn_raw >= 0) & (nn_raw < NB) &
                            (j >= 0) & (j < BS);
            j = j < 0 ? 0 : (j >= BS ? BS - 1 : j);
            const int ddc = dd < 3 ? dd : 2;
            const float raw = w[(size_t)ddc * BS * BS + (size_t)irow * BS + j];
            wlds[r][q] = ok ? raw : 0.f;
        }
    }
    __syncthreads();

    const int i_base = chunk * ROWS_PER_WG + ty * RPT;
    const int jlo    = i_base - 1;

    const f32x4* __restrict__ x4 = (const f32x4*)x;
    f32x4* __restrict__ out4     = (f32x4*)out;

    // per-dd clamped block base pointers (OOB blocks clamped; weights are 0 there)
    const f32x4* xb[3];
#pragma unroll
    for (int dd = 0; dd < 3; ++dd) {
        int nn = n + dd - 1;
        nn = nn < 0 ? 0 : (nn >= NB ? NB - 1 : nn);
        xb[dd] = x4 + ((size_t)(b * NB + nn) * BS) * F4 + tx;
    }

    f32x4 acc[RPT];
#pragma unroll
    for (int i = 0; i < RPT; ++i) acc[i] = (f32x4)(0.f);

    // window row offsets (clamped; OOB rows covered by zero weights)
    size_t roff[RPT + 2];
#pragma unroll
    for (int jj = 0; jj < RPT + 2; ++jj) {
        int j = jlo + jj;
        j = j < 0 ? 0 : (j >= BS ? BS - 1 : j);
        roff[jj] = (size_t)j * F4;
    }

#define LOADW(V, DD)                                   \
    _Pragma("unroll")                                  \
    for (int jj = 0; jj < RPT + 2; ++jj)               \
        V[jj] = xb[DD][roff[jj]];

#define FMAW(V, DD)                                            \
    _Pragma("unroll")                                          \
    for (int ii = 0; ii < RPT; ++ii) {                         \
        const f32x4 wr = *(const f32x4*)&wlds[ty * RPT + ii][(DD) * 4]; \
        _Pragma("unroll")                                      \
        for (int c = 0; c < 3; ++c) {                          \
            const float s  = wr[c];                            \
            const f32x4 vv = V[ii + c];                        \
            acc[ii].x = fmaf(s, vv.x, acc[ii].x);              \
            acc[ii].y = fmaf(s, vv.y, acc[ii].y);              \
            acc[ii].z = fmaf(s, vv.z, acc[ii].z);              \
            acc[ii].w = fmaf(s, vv.w, acc[ii].w);              \
        }                                                      \
    }

    f32x4 v0[RPT + 2], v1[RPT + 2], v2[RPT + 2];
    LOADW(v0, 0)
    LOADW(v1, 1)
    FMAW(v0, 0)
    LOADW(v2, 2)
    FMAW(v1, 1)
    FMAW(v2, 2)

#undef LOADW
#undef FMAW

    const size_t obase = ((size_t)(b * NB + n) * BS + i_base) * F4 + tx;
#pragma unroll
    for (int i = 0; i < RPT; ++i)
        __builtin_nontemporal_store(acc[i], &out4[obase + (size_t)i * F4]);
}

extern "C" void kernel_launch(void* const* d_in, const int* in_sizes, int n_in,
                              void* d_out, int out_size, void* d_ws, size_t ws_size,
                              hipStream_t stream) {
    const float* x = (const float*)d_in[0];     // [4, 65536, 256] f32
    const float* w = (const float*)d_in[1];     // [3, 256, 256]   f32
    float* out = (float*)d_out;                 // [4, 65536, 256] f32

    dim3 block(64, TY);
    blockconv_kernel<<<NWG, block, 0, stream>>>(x, w, out);
}